// Round 8
// baseline (889.142 us; speedup 1.0000x reference)
//
#include <hip/hip_runtime.h>
#include <hip/hip_bf16.h>
#include <cstdint>

// Problem constants (EnBaseLayer: E(n)-GNN layer)
#define NN 50000
#define NE 600000
#define HD 128
#define NG 20
#define EF 4
#define K1 280            // 2H + NG + EF
#define TILES (NE/64)     // 9375
#define EGRID 512         // 2 blocks/CU resident
#define ROWU 148          // s_inp row stride in u32 (592 B = 37*16)
#define NTILE 782         // ceil(NN/64)
#define SW(r) ((r) ^ (((r)>>3)&7))   // LDS 16B-slot swizzle within 8-row group

typedef __attribute__((ext_vector_type(4))) float f32x4;
typedef __attribute__((ext_vector_type(8))) __bf16 bf16x8;
typedef __attribute__((ext_vector_type(4))) unsigned int u32x4;

__device__ __forceinline__ float fast_rcp(float x){ return __builtin_amdgcn_rcpf(x); }
__device__ __forceinline__ float silu_f(float x){ return x * fast_rcp(1.0f + __expf(-x)); }
__device__ __forceinline__ float sigmoid_f(float x){ return fast_rcp(1.0f + __expf(-x)); }
__device__ __forceinline__ float tanh_f(float x){ return 1.0f - 2.0f*fast_rcp(__expf(2.0f*x)+1.0f); }

__device__ __forceinline__ uint32_t pk2(float a, float b){   // RNE f32x2 -> bf16x2
  uint32_t ua = __float_as_uint(a); ua += 0x7FFFu + ((ua>>16)&1u);
  uint32_t ub = __float_as_uint(b); ub += 0x7FFFu + ((ub>>16)&1u);
  return (ua>>16) | (ub & 0xFFFF0000u);
}
__device__ __forceinline__ uint16_t bfb(float a){
  uint32_t ua = __float_as_uint(a); ua += 0x7FFFu + ((ua>>16)&1u);
  return (uint16_t)(ua>>16);
}
__device__ __forceinline__ float bf2f(uint16_t b){ return __uint_as_float(((uint32_t)b)<<16); }
__device__ __forceinline__ f32x4 MF(u32x4 a, u32x4 b, f32x4 c){
  return __builtin_amdgcn_mfma_f32_16x16x32_bf16(
      __builtin_bit_cast(bf16x8, a), __builtin_bit_cast(bf16x8, b), c, 0, 0, 0);
}

// ---------------------------------------------------------------------------
// Pre-kernels: h->bf16, CSR build (hist -> scan -> fill)
// ---------------------------------------------------------------------------
__global__ void __launch_bounds__(256) h2bf_kernel(
    const float* __restrict__ h, uint32_t* __restrict__ hb)
{
  const size_t i = ((size_t)blockIdx.x*256 + threadIdx.x)*8;
  const float4 a = *reinterpret_cast<const float4*>(h + i);
  const float4 b = *reinterpret_cast<const float4*>(h + i + 4);
  u32x4 v = {pk2(a.x,a.y), pk2(a.z,a.w), pk2(b.x,b.y), pk2(b.z,b.w)};
  *reinterpret_cast<u32x4*>(hb + i/2) = v;
}

__global__ void __launch_bounds__(512) hist_kernel(
    const int* __restrict__ ei, int* __restrict__ cnt)
{
  const int e = blockIdx.x*512 + threadIdx.x;
  if (e < NE) atomicAdd(&cnt[ei[NE + e]], 1);
}

__global__ void __launch_bounds__(512) scanA_kernel(
    int* __restrict__ cur, int* __restrict__ bsums)
{
  __shared__ int s[512];
  const int tid = threadIdx.x;
  const int i = blockIdx.x*512 + tid;
  const int v = (i < NN) ? cur[i] : 0;
  s[tid] = v; __syncthreads();
  #pragma unroll
  for (int d = 1; d < 512; d <<= 1){
    const int t = (tid >= d) ? s[tid-d] : 0;
    __syncthreads();
    s[tid] += t;
    __syncthreads();
  }
  if (i < NN) cur[i] = s[tid] - v;             // exclusive within block
  if (tid == 511) bsums[blockIdx.x] = s[511];  // block total
}

__global__ void scanB_kernel(int* __restrict__ bsums)
{
  if (threadIdx.x == 0 && blockIdx.x == 0){
    int acc = 0;
    for (int b = 0; b < 98; ++b){ const int t = bsums[b]; bsums[b] = acc; acc += t; }
  }
}

__global__ void __launch_bounds__(512) scanC_kernel(
    int* __restrict__ cur, const int* __restrict__ bsums)
{
  const int i = blockIdx.x*512 + threadIdx.x;
  if (i < NN) cur[i] += bsums[blockIdx.x];
}

__global__ void __launch_bounds__(512) fill_kernel(
    const int* __restrict__ ei, int* __restrict__ cur, int* __restrict__ perm)
{
  const int e = blockIdx.x*512 + threadIdx.x;
  if (e < NE){
    const int p = atomicAdd(&cur[ei[NE + e]], 1);
    perm[p] = e;
  }
}

// ---------------------------------------------------------------------------
// CSR edge kernel: 8 waves/block, tile = 64 dst-sorted edges (via perm).
// Wave w owns N-tile w (cols 16w..16w+15).
// A-frag: lane l holds row l&15, k = 32ks + 8*(l>>4) + j.
// D-frag: row(m)=4*(l>>4)+reg, col(n)=l&15.
// mi/dx segment-reduced in LDS per tile (slots over sorted dst runs), then
// flushed with U (~6) global atomics/row-of-128 instead of 64.
// uacc[64][128] f32 (32 KB) aliases s_inp (dead after GEMM1).
// LDS layout (u32 offsets): s_inp[0..9472) | t1f[9472..13568) (16 KB)
//   | mf_[13568..17664) (16 KB) | tl[17664..18448)
// ---------------------------------------------------------------------------
#define EDGE_LDS_U32 (64*ROWU + 4096 + 4096 + 784)
#define EDGE_LDS_B (EDGE_LDS_U32*4)   // 73792 B -> 2 blocks/CU (147.6/160 KB)

__global__ void __launch_bounds__(512, 4) edge_csr_kernel(
    const uint32_t* __restrict__ hb, const float* __restrict__ x,
    const int* __restrict__ ei, const float* __restrict__ eattr,
    const int* __restrict__ perm,
    const float* __restrict__ We1, const float* __restrict__ be1,
    const float* __restrict__ We2, const float* __restrict__ be2,
    const float* __restrict__ Winf, const float* __restrict__ binf,
    const float* __restrict__ Wx1, const float* __restrict__ bx1,
    const float* __restrict__ Wx2, float* __restrict__ out)
{
  extern __shared__ uint32_t smem[];
  uint32_t* s_inp = smem;                                   // [64][ROWU]; uacc aliases
  float*    uacc  = (float*)smem;                           // [64][128] f32
  uint16_t* t1f   = (uint16_t*)(smem + 64*ROWU);            // [16][64][8] u16 = 4096 u32
  uint16_t* mf_   = (uint16_t*)(smem + 64*ROWU + 4096);     // [16][64][8] u16 = 4096 u32
  uint32_t* tl    = smem + 64*ROWU + 8192;
  int*   s_dst  = (int*)tl;            // 64
  float* s_rel  = (float*)(tl+64);     // 192
  float* s_dist = (float*)(tl+256);    // 64
  float* s_pe   = (float*)(tl+320);    // 64
  float* s_pg   = (float*)(tl+384);    // 64
  int*   s_slot = (int*)(tl+448);      // 64
  int*   s_udst = (int*)(tl+512);      // 64
  float* s_uax  = (float*)(tl+576);    // 192 (dx per-slot acc)
  int*   s_Un   = (int*)(tl+768);      // 1

  const int tid = threadIdx.x;
  const int w = tid >> 6, l = tid & 63;
  const int lo = l & 15, hi = l >> 4;
  const int col = w*16 + lo;
  const int r8 = tid >> 3, p8 = tid & 7;
  const int ks2 = w >> 1;
  const int lp  = ((w&1)*2 + (lo>>3))*16 + 4*hi;
  const int jj  = lo & 7;
  const int lsw = SW(l);

  // ---- persistent weight B-fragments (17 frags = 68 regs) ----
  u32x4 B1[9], B2[4], B3[4];
  #pragma unroll
  for (int ks = 0; ks < 9; ++ks){
    float f[8];
    #pragma unroll
    for (int j = 0; j < 8; ++j){
      const int k = ks*32 + hi*8 + j;
      f[j] = (k < K1) ? We1[k*HD + col] : 0.0f;
    }
    B1[ks] = {pk2(f[0],f[1]), pk2(f[2],f[3]), pk2(f[4],f[5]), pk2(f[6],f[7])};
  }
  #pragma unroll
  for (int ks = 0; ks < 4; ++ks){
    float f2[8], f3[8];
    #pragma unroll
    for (int j = 0; j < 8; ++j){
      const int k = ks*32 + hi*8 + j;
      f2[j] = We2[k*HD + col];
      f3[j] = Wx1[k*HD + col];
    }
    B2[ks] = {pk2(f2[0],f2[1]), pk2(f2[2],f2[3]), pk2(f2[4],f2[5]), pk2(f2[6],f2[7])};
    B3[ks] = {pk2(f3[0],f3[1]), pk2(f3[2],f3[3]), pk2(f3[4],f3[5]), pk2(f3[6],f3[7])};
  }
  const float vbe1 = be1[col], vbe2 = be2[col], vbx1 = bx1[col];
  const float wi = Winf[col], wx = Wx2[col], vbinf = binf[0];
  const float SP = 10.0f/19.0f;
  const float CO = -0.5f/(SP*SP);

  for (int t = blockIdx.x; t < TILES; t += EGRID){
    const int ebase = t*64;
    __syncthreads();   // (1) prior flush done; uacc/s_* reusable

    // ---- phase A (tid<64, wave 0): perm->edge, geometry, slots, gauss ----
    if (tid < 64){
      const int e = perm[ebase + tid];
      const int sj = ei[e], dj = ei[NE + e];
      const float ax = x[dj*3+0]-x[sj*3+0];
      const float ay = x[dj*3+1]-x[sj*3+1];
      const float az = x[dj*3+2]-x[sj*3+2];
      const float dd = sqrtf(ax*ax + ay*ay + az*az + 1e-8f);
      s_dst[tid] = dj;
      s_rel[3*tid+0]=ax; s_rel[3*tid+1]=ay; s_rel[3*tid+2]=az;
      s_dist[tid]=dd; s_pe[tid]=0.0f; s_pg[tid]=0.0f;
      // segment slots over sorted dst run-lengths (wave-ballot scan)
      const int dprev = __shfl_up(dj, 1);
      const int isnew = (tid == 0) || (dj != dprev);
      const unsigned long long m = __ballot(isnew);
      const int slot = __popcll(m << (63 - tid)) - 1;
      s_slot[tid] = slot;
      if (isnew) s_udst[slot] = dj;
      if (tid == 63) s_Un[0] = slot + 1;
      // dx slot accumulators zero
      s_uax[3*tid+0]=0.0f; s_uax[3*tid+1]=0.0f; s_uax[3*tid+2]=0.0f;
      // gauss smearing + edge_attr columns
      float g[24];
      #pragma unroll
      for (int j = 0; j < 20; ++j){ const float a = dd - j*SP; g[j] = __expf(CO*a*a); }
      const float4 e4 = *reinterpret_cast<const float4*>(eattr + (size_t)e*EF);
      g[20]=e4.x; g[21]=e4.y; g[22]=e4.z; g[23]=e4.w;
      uint32_t* gp = s_inp + tid*ROWU + 128;
      u32x4 g0v = {pk2(g[0],g[1]),  pk2(g[2],g[3]),  pk2(g[4],g[5]),  pk2(g[6],g[7])};
      u32x4 g1v = {pk2(g[8],g[9]),  pk2(g[10],g[11]),pk2(g[12],g[13]),pk2(g[14],g[15])};
      u32x4 g2v = {pk2(g[16],g[17]),pk2(g[18],g[19]),pk2(g[20],g[21]),pk2(g[22],g[23])};
      u32x4 g3v = {0,0,0,0};
      *reinterpret_cast<u32x4*>(gp)    = g0v;
      *reinterpret_cast<u32x4*>(gp+4)  = g1v;
      *reinterpret_cast<u32x4*>(gp+8)  = g2v;
      *reinterpret_cast<u32x4*>(gp+12) = g3v;
    }
    // ---- phase B: gather bf16 h rows (dst rows mostly shared -> L1 hits) ----
    {
      const int e = perm[ebase + r8];
      const int node = (p8 < 4) ? ei[NE + e] : ei[e];   // cols 0..127 = h[dst]
      const uint32_t* hw = hb + (size_t)node*(HD/2) + (p8&3)*16;
      uint32_t* dp = s_inp + r8*ROWU + p8*16;
      #pragma unroll
      for (int q = 0; q < 4; ++q)
        *reinterpret_cast<u32x4*>(dp + 4*q) = *reinterpret_cast<const u32x4*>(hw + 4*q);
    }
    __syncthreads();   // (3) tile staged

    // ---------------- GEMM1: t1 = silu(inp @ We1 + be1) ----------------
    #pragma unroll
    for (int Mt = 0; Mt < 4; ++Mt){
      const uint32_t* arow = s_inp + (Mt*16 + lo)*ROWU + hi*4;
      f32x4 acc = {0,0,0,0};
      #pragma unroll
      for (int ks = 0; ks < 9; ++ks)
        acc = MF(*reinterpret_cast<const u32x4*>(arow + ks*16), B1[ks], acc);
      #pragma unroll
      for (int reg = 0; reg < 4; ++reg)
        t1f[((Mt*4 + ks2)*64 + SW(lp+reg))*8 + jj] = bfb(silu_f(acc[reg] + vbe1));
    }
    __syncthreads();   // (5) t1f ready; s_inp dead -> uacc usable

    // ---- zero uacc rows [0..U) (aliases s_inp) ----
    const int U = s_Un[0];
    for (int idx = tid; idx < U*32; idx += 512)
      *reinterpret_cast<u32x4*>((uint32_t*)uacc + idx*4) = u32x4{0,0,0,0};

    // ---------------- GEMM2: mij = silu(t1 @ We2 + be2); eij partials ----
    #pragma unroll
    for (int Mt = 0; Mt < 4; ++Mt){
      f32x4 acc = {0,0,0,0};
      #pragma unroll
      for (int ks = 0; ks < 4; ++ks)
        acc = MF(*reinterpret_cast<const u32x4*>(t1f + ((Mt*4+ks)*64 + lsw)*8), B2[ks], acc);
      float p[4];
      #pragma unroll
      for (int reg = 0; reg < 4; ++reg){
        const float m = silu_f(acc[reg] + vbe2);
        mf_[((Mt*4 + ks2)*64 + SW(lp+reg))*8 + jj] = bfb(m);
        p[reg] = m * wi;
      }
      #pragma unroll
      for (int msk = 1; msk < 16; msk <<= 1){
        #pragma unroll
        for (int reg = 0; reg < 4; ++reg) p[reg] += __shfl_xor(p[reg], msk);
      }
      if (lo == 0){
        #pragma unroll
        for (int reg = 0; reg < 4; ++reg) atomicAdd(&s_pe[Mt*16 + 4*hi + reg], p[reg]);
      }
    }
    __syncthreads();   // (7) mf_ + s_pe + uacc-zero ready

    // ---- mi segment-accumulate into LDS uacc[slot][col] ----
    #pragma unroll
    for (int Mt = 0; Mt < 4; ++Mt){
      #pragma unroll
      for (int reg = 0; reg < 4; ++reg){
        const int r = Mt*16 + 4*hi + reg;
        const float eij = sigmoid_f(s_pe[r] + vbinf);
        const float m = bf2f(mf_[((Mt*4 + ks2)*64 + SW(lp+reg))*8 + jj]);
        atomicAdd(&uacc[s_slot[r]*HD + col], m*eij);
      }
    }
    // ---------------- GEMM3: gate partials ----------------
    #pragma unroll
    for (int Mt = 0; Mt < 4; ++Mt){
      f32x4 acc = {0,0,0,0};
      #pragma unroll
      for (int ks = 0; ks < 4; ++ks)
        acc = MF(*reinterpret_cast<const u32x4*>(mf_ + ((Mt*4+ks)*64 + lsw)*8), B3[ks], acc);
      float p[4];
      #pragma unroll
      for (int reg = 0; reg < 4; ++reg)
        p[reg] = silu_f(acc[reg] + vbx1) * wx;
      #pragma unroll
      for (int msk = 1; msk < 16; msk <<= 1){
        #pragma unroll
        for (int reg = 0; reg < 4; ++reg) p[reg] += __shfl_xor(p[reg], msk);
      }
      if (lo == 0){
        #pragma unroll
        for (int reg = 0; reg < 4; ++reg) atomicAdd(&s_pg[Mt*16 + 4*hi + reg], p[reg]);
      }
    }
    __syncthreads();   // (9) s_pg + uacc ready

    // ---- dx segment-accumulate into LDS ----
    if (tid < 192){
      const int er = tid/3, c = tid - 3*er;
      const float gate = tanh_f(s_pg[er]);
      const float sc = gate * fast_rcp(s_dist[er] + 1.0f);
      atomicAdd(&s_uax[s_slot[er]*3 + c], s_rel[3*er+c]*sc);
    }
    __syncthreads();   // (10) all LDS accumulation done

    // ---- flush: U*(128+3) global atomics instead of 64*(128+3) ----
    {
      const int c = tid & 127;
      for (int u = tid >> 7; u < U; u += 4)
        atomicAdd(out + (size_t)s_udst[u]*HD + c, uacc[u*HD + c]);
      for (int q = tid; q < U*3; q += 512){
        const int u = q/3, cc = q - 3*u;
        atomicAdd(out + (size_t)NN*HD + (size_t)s_udst[u]*3 + cc, s_uax[q]);
      }
    }
  }
}

// ---------------------------------------------------------------------------
// Fallback edge kernel (round 6, f32-h, per-edge atomics) for small ws_size.
// ---------------------------------------------------------------------------
#define FB_LDS_U32 (64*ROWU + 4096 + 4096 + 448)
#define FB_LDS_B (FB_LDS_U32*4)

__global__ void __launch_bounds__(512, 4) edge_fb_kernel(
    const float* __restrict__ h, const float* __restrict__ x,
    const int* __restrict__ ei, const float* __restrict__ eattr,
    const float* __restrict__ We1, const float* __restrict__ be1,
    const float* __restrict__ We2, const float* __restrict__ be2,
    const float* __restrict__ Winf, const float* __restrict__ binf,
    const float* __restrict__ Wx1, const float* __restrict__ bx1,
    const float* __restrict__ Wx2, float* __restrict__ out)
{
  extern __shared__ uint32_t smem[];
  uint32_t* s_inp = smem;
  uint16_t* t1f   = (uint16_t*)(smem + 64*ROWU);
  uint16_t* mf_   = (uint16_t*)(smem + 64*ROWU + 4096);
  uint32_t* tl    = smem + 64*ROWU + 8192;
  int*   s_dst  = (int*)tl;
  float* s_rel  = (float*)(tl+64);
  float* s_dist = (float*)(tl+256);
  float* s_pe   = (float*)(tl+320);
  float* s_pg   = (float*)(tl+384);

  const int tid = threadIdx.x;
  const int w = tid >> 6, l = tid & 63;
  const int lo = l & 15, hi = l >> 4;
  const int col = w*16 + lo;
  const int r8 = tid >> 3, p8 = tid & 7;
  const int ks2 = w >> 1;
  const int lp  = ((w&1)*2 + (lo>>3))*16 + 4*hi;
  const int jj  = lo & 7;
  const int lsw = SW(l);

  u32x4 B1[9], B2[4], B3[4];
  #pragma unroll
  for (int ks = 0; ks < 9; ++ks){
    float f[8];
    #pragma unroll
    for (int j = 0; j < 8; ++j){
      const int k = ks*32 + hi*8 + j;
      f[j] = (k < K1) ? We1[k*HD + col] : 0.0f;
    }
    B1[ks] = {pk2(f[0],f[1]), pk2(f[2],f[3]), pk2(f[4],f[5]), pk2(f[6],f[7])};
  }
  #pragma unroll
  for (int ks = 0; ks < 4; ++ks){
    float f2[8], f3[8];
    #pragma unroll
    for (int j = 0; j < 8; ++j){
      const int k = ks*32 + hi*8 + j;
      f2[j] = We2[k*HD + col];
      f3[j] = Wx1[k*HD + col];
    }
    B2[ks] = {pk2(f2[0],f2[1]), pk2(f2[2],f2[3]), pk2(f2[4],f2[5]), pk2(f2[6],f2[7])};
    B3[ks] = {pk2(f3[0],f3[1]), pk2(f3[2],f3[3]), pk2(f3[4],f3[5]), pk2(f3[6],f3[7])};
  }
  const float vbe1 = be1[col], vbe2 = be2[col], vbx1 = bx1[col];
  const float wi = Winf[col], wx = Wx2[col], vbinf = binf[0];
  const float SP = 10.0f/19.0f;
  const float CO = -0.5f/(SP*SP);

  for (int t = blockIdx.x; t < TILES; t += EGRID){
    const int ebase = t*64;
    __syncthreads();
    if (tid < 64){
      const int sj = ei[ebase+tid], dj = ei[NE+ebase+tid];
      const float ax = x[dj*3+0]-x[sj*3+0];
      const float ay = x[dj*3+1]-x[sj*3+1];
      const float az = x[dj*3+2]-x[sj*3+2];
      const float dd = sqrtf(ax*ax + ay*ay + az*az + 1e-8f);
      s_dst[tid] = dj;
      s_rel[3*tid+0]=ax; s_rel[3*tid+1]=ay; s_rel[3*tid+2]=az;
      s_dist[tid]=dd; s_pe[tid]=0.0f; s_pg[tid]=0.0f;
      float g[24];
      #pragma unroll
      for (int j = 0; j < 20; ++j){ const float a = dd - j*SP; g[j] = __expf(CO*a*a); }
      const float4 e4 = *reinterpret_cast<const float4*>(eattr + (size_t)(ebase+tid)*EF);
      g[20]=e4.x; g[21]=e4.y; g[22]=e4.z; g[23]=e4.w;
      uint32_t* gp = s_inp + tid*ROWU + 128;
      u32x4 g0v = {pk2(g[0],g[1]),  pk2(g[2],g[3]),  pk2(g[4],g[5]),  pk2(g[6],g[7])};
      u32x4 g1v = {pk2(g[8],g[9]),  pk2(g[10],g[11]),pk2(g[12],g[13]),pk2(g[14],g[15])};
      u32x4 g2v = {pk2(g[16],g[17]),pk2(g[18],g[19]),pk2(g[20],g[21]),pk2(g[22],g[23])};
      u32x4 g3v = {0,0,0,0};
      *reinterpret_cast<u32x4*>(gp)    = g0v;
      *reinterpret_cast<u32x4*>(gp+4)  = g1v;
      *reinterpret_cast<u32x4*>(gp+8)  = g2v;
      *reinterpret_cast<u32x4*>(gp+12) = g3v;
    }
    {
      const int e = ebase + r8;
      const int node = (p8 < 4) ? ei[NE + e] : ei[e];
      const float* hp = h + (size_t)node*HD + (p8&3)*32;
      uint32_t* dp = s_inp + r8*ROWU + p8*16;
      #pragma unroll
      for (int q = 0; q < 4; ++q){
        const float4 va = *reinterpret_cast<const float4*>(hp + 8*q);
        const float4 vb = *reinterpret_cast<const float4*>(hp + 8*q + 4);
        u32x4 v = { pk2(va.x,va.y), pk2(va.z,va.w), pk2(vb.x,vb.y), pk2(vb.z,vb.w) };
        *reinterpret_cast<u32x4*>(dp + 4*q) = v;
      }
    }
    __syncthreads();

    #pragma unroll
    for (int Mt = 0; Mt < 4; ++Mt){
      const uint32_t* arow = s_inp + (Mt*16 + lo)*ROWU + hi*4;
      f32x4 acc = {0,0,0,0};
      #pragma unroll
      for (int ks = 0; ks < 9; ++ks)
        acc = MF(*reinterpret_cast<const u32x4*>(arow + ks*16), B1[ks], acc);
      #pragma unroll
      for (int reg = 0; reg < 4; ++reg)
        t1f[((Mt*4 + ks2)*64 + SW(lp+reg))*8 + jj] = bfb(silu_f(acc[reg] + vbe1));
    }
    __syncthreads();

    #pragma unroll
    for (int Mt = 0; Mt < 4; ++Mt){
      f32x4 acc = {0,0,0,0};
      #pragma unroll
      for (int ks = 0; ks < 4; ++ks)
        acc = MF(*reinterpret_cast<const u32x4*>(t1f + ((Mt*4+ks)*64 + lsw)*8), B2[ks], acc);
      float p[4];
      #pragma unroll
      for (int reg = 0; reg < 4; ++reg){
        const float m = silu_f(acc[reg] + vbe2);
        mf_[((Mt*4 + ks2)*64 + SW(lp+reg))*8 + jj] = bfb(m);
        p[reg] = m * wi;
      }
      #pragma unroll
      for (int msk = 1; msk < 16; msk <<= 1){
        #pragma unroll
        for (int reg = 0; reg < 4; ++reg) p[reg] += __shfl_xor(p[reg], msk);
      }
      if (lo == 0){
        #pragma unroll
        for (int reg = 0; reg < 4; ++reg) atomicAdd(&s_pe[Mt*16 + 4*hi + reg], p[reg]);
      }
    }
    __syncthreads();

    #pragma unroll
    for (int Mt = 0; Mt < 4; ++Mt){
      #pragma unroll
      for (int reg = 0; reg < 4; ++reg){
        const int r = Mt*16 + 4*hi + reg;
        const float eij = sigmoid_f(s_pe[r] + vbinf);
        const float m = bf2f(mf_[((Mt*4 + ks2)*64 + SW(lp+reg))*8 + jj]);
        atomicAdd(out + (size_t)s_dst[r]*HD + col, m*eij);
      }
    }
    #pragma unroll
    for (int Mt = 0; Mt < 4; ++Mt){
      f32x4 acc = {0,0,0,0};
      #pragma unroll
      for (int ks = 0; ks < 4; ++ks)
        acc = MF(*reinterpret_cast<const u32x4*>(mf_ + ((Mt*4+ks)*64 + lsw)*8), B3[ks], acc);
      float p[4];
      #pragma unroll
      for (int reg = 0; reg < 4; ++reg)
        p[reg] = silu_f(acc[reg] + vbx1) * wx;
      #pragma unroll
      for (int msk = 1; msk < 16; msk <<= 1){
        #pragma unroll
        for (int reg = 0; reg < 4; ++reg) p[reg] += __shfl_xor(p[reg], msk);
      }
      if (lo == 0){
        #pragma unroll
        for (int reg = 0; reg < 4; ++reg) atomicAdd(&s_pg[Mt*16 + 4*hi + reg], p[reg]);
      }
    }
    __syncthreads();

    if (tid < 192){
      const int er = tid/3, c = tid - 3*er;
      const float gate = tanh_f(s_pg[er]);
      const float sc = gate * fast_rcp(s_dist[er] + 1.0f);
      atomicAdd(out + (size_t)NN*HD + (size_t)s_dst[er]*3 + c, s_rel[3*er+c]*sc);
    }
  }
}

// ---------------------------------------------------------------------------
// Node kernel (MFMA), unchanged.
// ---------------------------------------------------------------------------
#define CROW 132

__global__ void __launch_bounds__(512, 4) node_kernel(
    const float* __restrict__ h, const float* __restrict__ x,
    const float* __restrict__ mask,
    const float* __restrict__ Wn1, const float* __restrict__ bn1,
    const float* __restrict__ Wn2, const float* __restrict__ bn2,
    float* __restrict__ out)
{
  __shared__ uint32_t s_cat[64*CROW];
  __shared__ __align__(16) uint16_t t1n[4*4*64*8];

  const int tid = threadIdx.x;
  const int w = tid >> 6, l = tid & 63;
  const int lo = l & 15, hi = l >> 4;
  const int col = w*16 + lo;

  u32x4 Bn1[8], Bn2[4];
  #pragma unroll
  for (int ks = 0; ks < 8; ++ks){
    float f[8];
    #pragma unroll
    for (int j = 0; j < 8; ++j) f[j] = Wn1[(ks*32 + hi*8 + j)*HD + col];
    Bn1[ks] = {pk2(f[0],f[1]), pk2(f[2],f[3]), pk2(f[4],f[5]), pk2(f[6],f[7])};
  }
  #pragma unroll
  for (int ks = 0; ks < 4; ++ks){
    float f[8];
    #pragma unroll
    for (int j = 0; j < 8; ++j) f[j] = Wn2[(ks*32 + hi*8 + j)*HD + col];
    Bn2[ks] = {pk2(f[0],f[1]), pk2(f[2],f[3]), pk2(f[4],f[5]), pk2(f[6],f[7])};
  }
  const float vbn1 = bn1[col], vbn2 = bn2[col];
  const int nbase = blockIdx.x*64;
  const int ks2 = w >> 1;
  const int lp  = ((w&1)*2 + (lo>>3))*16 + 4*hi;
  const int jj  = lo & 7;

  {
    const int r = tid >> 3, p = tid & 7;
    const int n = nbase + r;
    uint32_t* dp = s_cat + r*CROW + p*16;
    if (n < NN){
      const float* sp = (p < 4) ? (out + (size_t)n*HD + p*32)
                                : (h   + (size_t)n*HD + (p-4)*32);
      #pragma unroll
      for (int q = 0; q < 8; ++q){
        const float4 v = *reinterpret_cast<const float4*>(sp + 4*q);
        dp[2*q]   = pk2(v.x, v.y);
        dp[2*q+1] = pk2(v.z, v.w);
      }
    } else {
      #pragma unroll
      for (int q = 0; q < 16; ++q) dp[q] = 0u;
    }
  }
  __syncthreads();

  #pragma unroll
  for (int Mt = 0; Mt < 4; ++Mt){
    const uint32_t* arow = s_cat + (Mt*16 + lo)*CROW + hi*4;
    f32x4 acc = {0,0,0,0};
    #pragma unroll
    for (int ks = 0; ks < 8; ++ks)
      acc = MF(*reinterpret_cast<const u32x4*>(arow + ks*16), Bn1[ks], acc);
    uint16_t* tp = t1n + ((Mt*4 + ks2)*64 + lp)*8 + jj;
    #pragma unroll
    for (int reg = 0; reg < 4; ++reg)
      tp[reg*8] = bfb(silu_f(acc[reg] + vbn1));
  }
  __syncthreads();

  #pragma unroll
  for (int Mt = 0; Mt < 4; ++Mt){
    f32x4 acc = {0,0,0,0};
    #pragma unroll
    for (int ks = 0; ks < 4; ++ks)
      acc = MF(*reinterpret_cast<const u32x4*>(t1n + ((Mt*4+ks)*64 + l)*8), Bn2[ks], acc);
    #pragma unroll
    for (int reg = 0; reg < 4; ++reg){
      const int n = nbase + Mt*16 + 4*hi + reg;
      if (n < NN)
        out[(size_t)n*HD + col] = h[(size_t)n*HD + col] + acc[reg] + vbn2;
    }
  }

  if (tid < 192){
    const int r = tid/3, c = tid - 3*r;
    const int n = nbase + r;
    if (n < NN){
      const size_t ix = (size_t)NN*HD + (size_t)n*3 + c;
      out[ix] = x[(size_t)n*3 + c] + out[ix]*mask[n];
    }
  }
}

extern "C" void kernel_launch(void* const* d_in, const int* in_sizes, int n_in,
                              void* d_out, int out_size, void* d_ws, size_t ws_size,
                              hipStream_t stream) {
  (void)in_sizes; (void)n_in;
  const float* h    = (const float*)d_in[0];
  const float* x    = (const float*)d_in[1];
  const int*   ei   = (const int*)  d_in[2];
  const float* mask = (const float*)d_in[3];
  const float* ea   = (const float*)d_in[4];
  const float* We1  = (const float*)d_in[5];
  const float* be1  = (const float*)d_in[6];
  const float* We2  = (const float*)d_in[7];
  const float* be2  = (const float*)d_in[8];
  const float* Winf = (const float*)d_in[9];
  const float* binf = (const float*)d_in[10];
  const float* Wx1  = (const float*)d_in[11];
  const float* bx1  = (const float*)d_in[12];
  const float* Wx2  = (const float*)d_in[13];
  const float* Wn1  = (const float*)d_in[14];
  const float* bn1  = (const float*)d_in[15];
  const float* Wn2  = (const float*)d_in[16];
  const float* bn2  = (const float*)d_in[17];
  float* out = (float*)d_out;

  // ws layout (u32): hb[3,200,000] | cursor[50,000] | perm[600,000] | bsums[128]
  uint32_t* hb   = (uint32_t*)d_ws;
  int* cursor    = (int*)d_ws + 3200000;
  int* perm      = (int*)d_ws + 3250000;
  int* bsums     = (int*)d_ws + 3850000;
  const size_t need = (size_t)(3850000 + 128) * 4;
  const bool use_csr = ws_size >= need;

  hipFuncSetAttribute(reinterpret_cast<const void*>(edge_csr_kernel),
                      hipFuncAttributeMaxDynamicSharedMemorySize, EDGE_LDS_B);
  hipFuncSetAttribute(reinterpret_cast<const void*>(edge_fb_kernel),
                      hipFuncAttributeMaxDynamicSharedMemorySize, FB_LDS_B);

  // out[0..NN*HD) accumulates mi; out[NN*HD..) accumulates delta_x
  hipMemsetAsync(d_out, 0, (size_t)out_size * sizeof(float), stream);

  if (use_csr){
    hipMemsetAsync(cursor, 0, (size_t)NN*4, stream);
    h2bf_kernel<<<3125, 256, 0, stream>>>(h, hb);
    hist_kernel<<<1172, 512, 0, stream>>>(ei, cursor);
    scanA_kernel<<<98, 512, 0, stream>>>(cursor, bsums);
    scanB_kernel<<<1, 64, 0, stream>>>(bsums);
    scanC_kernel<<<98, 512, 0, stream>>>(cursor, bsums);
    fill_kernel<<<1172, 512, 0, stream>>>(ei, cursor, perm);
    edge_csr_kernel<<<EGRID, 512, EDGE_LDS_B, stream>>>(
        hb, x, ei, ea, perm, We1, be1, We2, be2, Winf, binf, Wx1, bx1, Wx2, out);
  } else {
    edge_fb_kernel<<<EGRID, 512, FB_LDS_B, stream>>>(
        h, x, ei, ea, We1, be1, We2, be2, Winf, binf, Wx1, bx1, Wx2, out);
  }
  node_kernel<<<NTILE, 512, 0, stream>>>(
      h, x, mask, Wn1, bn1, Wn2, bn2, out);
}